// Round 6
// baseline (61.689 us; speedup 1.0000x reference)
//
#include <hip/hip_runtime.h>
#include <hip/hip_bf16.h>
#include <stdint.h>

// Recommender: B=4096 users, L=200 history, D=64 emb, F=100000 films.
// Single fused kernel, one 512-thread block per user.
// Pass 1 (coalesced): wave w owns rows l = w+8i, lane = dim d. Each row is one
//   256B coalesced load, 25 independent loads/wave. min/max/sum per (w,d) in
//   regs; 16-bit sortable keys pair-packed to LDS keys[d][w*28+i] (w==sub).
// Pass 2: select-lane (sub,dloc) reads its 28 keys contiguously as 7 b64 --
//   words land directly in the dual 16x16 bit-transpose input layout. Bit-
//   serial popc median select (verified, absmax 0).
// Stats reduce via LDS partials; L2-normalize ue(256); fused MLP
// 320->128->64->1 + sigmoid (MLP buffers union'd over dead key region).

#define B_ 4096
#define L_ 200
#define D_ 64
#define LPAD 224      // 8 * max cmax4
#define KP_U16 228    // per-dim key pitch in u16 (456 B, multiple of 8 B)

__global__ __launch_bounds__(512) void fused_kernel(
    const int* __restrict__ film_hist,
    const float* __restrict__ ratings,
    const int* __restrict__ lengths,
    const int* __restrict__ film_indices,
    const float* __restrict__ emb,
    const float* __restrict__ W1, const float* __restrict__ b1,
    const float* __restrict__ W2, const float* __restrict__ b2,
    const float* __restrict__ W3, const float* __restrict__ b3,
    float* __restrict__ out)
{
  __shared__ int   hist_s[LPAD];
  __shared__ float rat_s[LPAD];
  __shared__ float red[8];
  __shared__ float ue[4*D_];                 // [min|max|mean|med]
  __shared__ float xls[320];                 // [ue_norm(256) | fe(64)]
  __shared__ float red3[3*512];              // min/max/sum partials [3][8][64]
  __shared__ union {
    uint16_t keys[D_*KP_U16];                // 29184 B, live until select done
    struct { float ph[512]; float h1s[128]; float h2s[64]; } m;  // MLP phase
  } sh;

  const int b = blockIdx.x;
  const int t = threadIdx.x;
  const int w = t >> 6;                      // wave id (pass1: row group; ==sub)
  const int lane = t & 63;                   // pass1: dim d
  const int n = lengths[b];
  const int cmax  = (n + 7) >> 3;            // <=25, block-uniform
  const int cmax4 = (cmax + 3) & ~3;         // multiple of 4, <=28

  // stage history + ratings; film embedding into xls[256..319]
  float r = 0.f;
  if (t < n) {
    hist_s[t] = film_hist[(size_t)b*L_ + t];
    float rv = ratings[(size_t)b*L_ + t];
    rat_s[t] = rv; r = rv;
  }
  if (t >= 448) {
    int fi = film_indices[b];
    xls[256 + (t-448)] = emb[(size_t)fi*D_ + (t-448)];
  }

  // mean rating (block reduce; t>=n contribute 0)
  float s = r;
  #pragma unroll
  for (int off = 32; off; off >>= 1) s += __shfl_down(s, off);
  if (lane == 0) red[w] = s;
  __syncthreads();
  const float mean_r = (red[0]+red[1]+red[2]+red[3]+red[4]+red[5]+red[6]+red[7]) / (float)n;
  const float mr1 = 0.1f - mean_r;

  // pad hist/rat up to 8*cmax4 with the last valid entry
  for (int l = n + t; l < 8*cmax4; l += 512) {
    hist_s[l] = hist_s[n-1];
    rat_s[l]  = rat_s[n-1];
  }
  __syncthreads();

  // ---- pass 1: coalesced gather + stats + key writes ----
  float vmin = __builtin_inff(), vmax = -__builtin_inff(), vsum = 0.f;
  uint16_t* kout = sh.keys + lane*KP_U16 + w*28;
  #pragma unroll
  for (int ch = 0; ch < 7; ++ch) {
    if (ch*4 < cmax4) {                      // block-uniform guard
      float vv[4], wg[4];
      int   ll[4];
      #pragma unroll
      for (int j = 0; j < 4; ++j) ll[j] = w + 8*(ch*4 + j);
      #pragma unroll
      for (int j = 0; j < 4; ++j) vv[j] = emb[(size_t)hist_s[ll[j]]*D_ + lane];
      #pragma unroll
      for (int j = 0; j < 4; ++j) wg[j] = rat_s[ll[j]] + mr1;
      uint32_t kk[4];
      #pragma unroll
      for (int j = 0; j < 4; ++j) {
        const float wv = vv[j] * wg[j];
        vmin = fminf(vmin, wv); vmax = fmaxf(vmax, wv);
        vsum += (ll[j] < n) ? wv : 0.f;
        uint32_t u = __float_as_uint(wv);
        kk[j] = (u ^ (0x80000000u | (uint32_t)((int32_t)u >> 31))) >> 16;  // sortable 16b
      }
      uint2 pr;
      pr.x = kk[0] | (kk[1] << 16);
      pr.y = kk[2] | (kk[3] << 16);
      *(uint2*)(kout + ch*4) = pr;           // 8B-aligned: lane*456 + w*56 + ch*8
    }
  }
  red3[t] = vmin; red3[512 + t] = vmax; red3[1024 + t] = vsum;
  __syncthreads();

  // ---- stats reduce (t<192) ----
  if (t < 64) {
    float m = red3[t];
    #pragma unroll
    for (int ww = 1; ww < 8; ++ww) m = fminf(m, red3[ww*64 + t]);
    ue[t] = m;
  } else if (t < 128) {
    const int dd = t - 64;
    float m = red3[512 + dd];
    #pragma unroll
    for (int ww = 1; ww < 8; ++ww) m = fmaxf(m, red3[512 + ww*64 + dd]);
    ue[64 + dd] = m;
  } else if (t < 192) {
    const int dd = t - 128;
    float m = red3[1024 + dd];
    #pragma unroll
    for (int ww = 1; ww < 8; ++ww) m += red3[1024 + ww*64 + dd];
    ue[128 + dd] = m / (float)n;
  }

  // ---- pass 2: median select. lane role: sub = lane>>3, d = w*8 + (lane&7) ----
  const int sub  = lane >> 3;
  const int dsel = w*8 + (lane & 7);
  const uint16_t* kp = sh.keys + dsel*KP_U16 + sub*28;
  uint32_t W[16];
  #pragma unroll
  for (int i = 0; i < 7; ++i) {
    uint2 v = *(const uint2*)(kp + 4*i);     // 4 keys; already k0|k1<<16 layout
    W[2*i] = v.x; W[2*i+1] = v.y;
  }
  W[14] = 0u; W[15] = 0u;

  // dual 16x16 bit-matrix transpose: plane for key-bit b is W[15-b];
  // key i sits at plane bit (15-(i>>1)) + 16*(i&1).
  #define XS(k, jj, m) { uint32_t tt = ((W[k] ^ (W[(k)|(jj)] >> (jj))) & (m)); \
                         W[k] ^= tt; W[(k)|(jj)] ^= (tt << (jj)); }
  XS(0,8,0x00FF00FFu) XS(1,8,0x00FF00FFu) XS(2,8,0x00FF00FFu) XS(3,8,0x00FF00FFu)
  XS(4,8,0x00FF00FFu) XS(5,8,0x00FF00FFu) XS(6,8,0x00FF00FFu) XS(7,8,0x00FF00FFu)
  XS(0,4,0x0F0F0F0Fu) XS(1,4,0x0F0F0F0Fu) XS(2,4,0x0F0F0F0Fu) XS(3,4,0x0F0F0F0Fu)
  XS(8,4,0x0F0F0F0Fu) XS(9,4,0x0F0F0F0Fu) XS(10,4,0x0F0F0F0Fu) XS(11,4,0x0F0F0F0Fu)
  XS(0,2,0x33333333u) XS(1,2,0x33333333u) XS(4,2,0x33333333u) XS(5,2,0x33333333u)
  XS(8,2,0x33333333u) XS(9,2,0x33333333u) XS(12,2,0x33333333u) XS(13,2,0x33333333u)
  XS(0,1,0x55555555u) XS(2,1,0x55555555u) XS(4,1,0x55555555u) XS(6,1,0x55555555u)
  XS(8,1,0x55555555u) XS(10,1,0x55555555u) XS(12,1,0x55555555u) XS(14,1,0x55555555u)
  #undef XS

  // bit-serial select of k-th smallest key (valid keys i in [0,c))
  const int c  = (n - sub + 7) >> 3;
  const int ce = (c + 1) >> 1, cf = c >> 1;
  uint32_t alive = ((1u << ce) - 1u) << (16 - ce);
  if (cf) alive |= ((1u << cf) - 1u) << (32 - cf);
  int k = (n - 1) >> 1;
  uint32_t prefix = 0;
  #pragma unroll
  for (int bb = 15; bb >= 0; --bb) {
    const uint32_t P = W[15 - bb];
    uint32_t z = alive & ~P;
    int cnt = __popc(z);
    cnt += __shfl_xor(cnt, 8);
    cnt += __shfl_xor(cnt, 16);
    cnt += __shfl_xor(cnt, 32);
    const bool zs = (k < cnt);
    alive  = zs ? z : (alive & P);
    k      = zs ? k : (k - cnt);
    prefix = zs ? prefix : (prefix | (1u << bb));
  }
  if (sub == 0) {
    uint32_t key32 = (prefix << 16) | 0x8000u;  // bucket midpoint
    float med = (prefix & 0x8000u) ? __uint_as_float(key32 ^ 0x80000000u)
                                   : __uint_as_float(~key32);
    ue[192 + dsel] = med;
  }
  __syncthreads();                           // ue complete; keys now dead

  // ---- L2-normalize ue into xls[0..255] ----
  float v = (t < 256) ? ue[t] : 0.f;
  float ss = v*v;
  #pragma unroll
  for (int off = 32; off; off >>= 1) ss += __shfl_down(ss, off);
  if (lane == 0) red[w] = ss;
  __syncthreads();
  const float rn2 = 1.0f / sqrtf(red[0]+red[1]+red[2]+red[3]+red[4]+red[5]+red[6]+red[7]);
  if (t < 256) xls[t] = v * rn2;
  __syncthreads();

  // ---- MLP h1 = relu(x @ W1 + b1): 128 outs, 4-way split dot ----
  {
    const int j = t & 127, q = t >> 7;
    const float* Wp = W1 + (size_t)(q*80)*128 + j;
    const float* xp = xls + q*80;
    float a0 = 0.f, a1 = 0.f;
    #pragma unroll 8
    for (int i = 0; i < 80; i += 2) {
      a0 += xp[i]   * Wp[(size_t)i*128];
      a1 += xp[i+1] * Wp[(size_t)(i+1)*128];
    }
    sh.m.ph[t] = a0 + a1;
  }
  __syncthreads();
  if (t < 128) sh.m.h1s[t] = fmaxf(b1[t] + sh.m.ph[t] + sh.m.ph[t+128]
                                         + sh.m.ph[t+256] + sh.m.ph[t+384], 0.f);
  __syncthreads();

  // ---- MLP h2 = relu(h1 @ W2 + b2): 64 outs, 8-way split dot ----
  {
    const int j = t & 63, q = t >> 6;
    const float* Wp = W2 + (size_t)(q*16)*64 + j;
    const float* hp = sh.m.h1s + q*16;
    float a = 0.f;
    #pragma unroll
    for (int i = 0; i < 16; ++i) a += hp[i] * Wp[(size_t)i*64];
    sh.m.ph[t] = a;
  }
  __syncthreads();
  if (t < 64) {
    float h = b2[t] + sh.m.ph[t] + sh.m.ph[t+64] + sh.m.ph[t+128] + sh.m.ph[t+192]
                    + sh.m.ph[t+256] + sh.m.ph[t+320] + sh.m.ph[t+384] + sh.m.ph[t+448];
    sh.m.h2s[t] = fmaxf(h, 0.f);
  }
  __syncthreads();

  // ---- out = sigmoid(h2 @ W3 + b3): wave 0 reduces 64 terms ----
  if (t < 64) {
    float vv = sh.m.h2s[t] * W3[t];
    #pragma unroll
    for (int off = 32; off; off >>= 1) vv += __shfl_down(vv, off);
    if (t == 0) out[b] = 1.f / (1.f + __expf(-(vv + b3[0])));
  }
}

extern "C" void kernel_launch(void* const* d_in, const int* in_sizes, int n_in,
                              void* d_out, int out_size, void* d_ws, size_t ws_size,
                              hipStream_t stream) {
  const int*   film_hist = (const int*)d_in[0];
  const float* ratings   = (const float*)d_in[1];
  const int*   lengths   = (const int*)d_in[2];
  const int*   film_idx  = (const int*)d_in[3];
  const float* emb       = (const float*)d_in[4];
  const float* W1 = (const float*)d_in[5];
  const float* b1 = (const float*)d_in[6];
  const float* W2 = (const float*)d_in[7];
  const float* b2 = (const float*)d_in[8];
  const float* W3 = (const float*)d_in[9];
  const float* b3 = (const float*)d_in[10];

  fused_kernel<<<B_, 512, 0, stream>>>(film_hist, ratings, lengths, film_idx, emb,
                                       W1, b1, W2, b2, W3, b3, (float*)d_out);
}